// Round 10
// baseline (376.482 us; speedup 1.0000x reference)
//
#include <hip/hip_runtime.h>
#include <math.h>

// Problem constants (unit_gcn): N=64, C=64, T=300, V=25, S=3
//
// ws float layout:
//   [2048, 4096)   : stats, 16 replicas x (sum[64], sumsq[64])
//   [4352, 10496)  : W-frag table ushort[12288]: frag f=((s*2+kt)*4+wv), elem lane*8+j
//   [10496, 12032) : A-frag table ushort[3072]:  frag f=(s*2+nt2), K-PERMUTED (R14)
//   byte 65536+    : ypre bf16, NATURAL [n][o][t][v], 61.44 MB (R16)
//
// R16: R15 helped (92.5->85.4, canary clean) but profile still all-idle
// (Mfma 10.3 / VALU 24 / HBM 21 / Occ 29): per-block compute (12 iters) is
// small vs fixed staging ramp + epilogue drain, and t=4 ILP can't fill the
// chains at ~9 waves/CU. t=6 per block (grid 50x64): +50% compute per
// stage/epilogue, 6-way ILP, 1/3 fewer block ramps. Regs: yacc 48 + frags
// 48 + temps ~= 130-140 < (256,3)=168 cap; LDS 23.5 KB -> 6 blocks/CU.
// ypre goes NATURAL layout (150 cols don't tile the old 100-chunks):
// k_main writes 300 B/o-row from LDS at 4 B grain; bnrelu simplifies to
// plane-contiguous u16x4 (no divide). Spill canary: WRITE must stay ~62.5.

typedef __attribute__((ext_vector_type(8))) short bf16x8;
typedef __attribute__((ext_vector_type(4))) float f32x4;
typedef __attribute__((ext_vector_type(4))) ushort u16x4;

__device__ inline ushort f2bf(float f) {
    union { float f; unsigned u; } v; v.f = f;
    unsigned r = v.u + 0x7fffu + ((v.u >> 16) & 1u);
    return (ushort)(r >> 16);
}
__device__ inline float bf2f(ushort h) {
    union { unsigned u; float f; } v; v.u = ((unsigned)h) << 16;
    return v.f;
}

// ---------------------------------------------------------------------------
// K1: 8 blocks. Normalize A (LDS), zero stats (block 0), build frag tables.
// ---------------------------------------------------------------------------
__global__ __launch_bounds__(256) void k_prep(const float* __restrict__ PA,
                                              const float* __restrict__ W,
                                              float* __restrict__ ws) {
    __shared__ float Al[1875];
    const int tid = threadIdx.x;
    const int bid = blockIdx.x;
    for (int i = tid; i < 1875; i += 256) Al[i] = PA[i];
    if (bid == 0)
        for (int i = tid; i < 2048; i += 256) ws[2048 + i] = 0.0f;
    __syncthreads();
    if (tid < 75) {
        int s = tid / 25, w = tid - s * 25;
        float ss = 0.0f;
        for (int v = 0; v < 25; ++v) {
            float p = Al[s * 625 + v * 25 + w];
            ss += p * p;
        }
        float inv = 1.0f / (sqrtf(ss) + 1e-4f);
        for (int v = 0; v < 25; ++v) Al[s * 625 + v * 25 + w] *= inv;
    }
    __syncthreads();
    int idx = bid * 256 + tid;
    if (idx < 1536) {  // W-frag: W[s][o=wv*16+col][c=kt*32+quad*8+j]
        ushort* wt = (ushort*)(ws + 4352);
        int lane = idx & 63, rest = idx >> 6;
        int wv = rest & 3, sk = rest >> 2;
        int kt = sk & 1, s = sk >> 1;
        int col = lane & 15, quad = lane >> 4;
        const float* wp = W + s * 4096 + (wv * 16 + col) * 64 + kt * 32 + quad * 8;
#pragma unroll
        for (int j = 0; j < 8; ++j) wt[idx * 8 + j] = f2bf(wp[j]);
    } else if (idx < 1920) {  // A-frag, K-PERMUTED: k=quad*8+j -> v below
        ushort* at = (ushort*)(ws + 10496);
        int a = idx - 1536;
        int lane = a & 63, rest = a >> 6;
        int nt2 = rest & 1, s = rest >> 1;
        int col = lane & 15, quad = lane >> 4;
        int w = nt2 * 16 + col;
#pragma unroll
        for (int j = 0; j < 8; ++j) {
            // j<4: v = quad*4+j (zA rows); j>=4: v = 16+quad*4+(j-4) (zB rows)
            int v = quad * 4 + (j < 4 ? j : j + 12);
            float av = (v < 25 && w < 25) ? Al[s * 625 + v * 25 + w] : 0.0f;
            at[a * 8 + j] = f2bf(av);
        }
    }
}

// ---------------------------------------------------------------------------
// K2: per block one n, 6 t-steps (grid 50 x 64).
//  All 12 fragments hoisted (R15); s,t fully unrolled (6-way ILP).
//  GEMM1 swapped -> Z^T, o lane-local; K-permuted A-frag table -> the
//  lane-local pack is GEMM2's A-operand directly (no shuffles, R14).
//  Epilogue: LDS-stage 64x150 tile (overlay Xl) -> natural-layout ypre,
//  per-o rows of 300 B at 4 B grain.
// LDS: Xl [160 rows][72] bf16 = 23 KB (rows 150..159 zero); Ys overlays.
// ---------------------------------------------------------------------------
__global__ __launch_bounds__(256, 3) void k_main16(const float* __restrict__ x,
                                                   const float* __restrict__ ws,
                                                   ushort* __restrict__ ypre,
                                                   float* __restrict__ stats) {
    __shared__ __align__(16) ushort Xl[160 * 72];
    __shared__ float sst[128];

    const int tid = threadIdx.x;
    const int wv = tid >> 6;
    const int lane = tid & 63;
    const int col = lane & 15;
    const int quad = lane >> 4;
    const int strip = wv << 4;
    const int n = blockIdx.y;
    const int bx = blockIdx.x;  // 0..49, covers t-frames [6bx, 6bx+6)

    const ushort* wt = (const ushort*)(ws + 4352);
    const ushort* at = (const ushort*)(ws + 10496);

    // hoist all 12 fragments (issued before staging; L3-hot)
    bf16x8 wf[6], af[6];
#pragma unroll
    for (int s = 0; s < 3; ++s) {
        wf[s * 2 + 0] = *(const bf16x8*)&wt[(((s * 2 + 0) * 4 + wv) * 64 + lane) * 8];
        wf[s * 2 + 1] = *(const bf16x8*)&wt[(((s * 2 + 1) * 4 + wv) * 64 + lane) * 8];
        af[s * 2 + 0] = *(const bf16x8*)&at[((s * 2 + 0) * 64 + lane) * 8];
        af[s * 2 + 1] = *(const bf16x8*)&at[((s * 2 + 1) * 64 + lane) * 8];
    }

    // stage X: x[n, c, bx*150 + tv] -> Xl[tv*72 + c], tv in [0,150)
    {
        const float* xr = x + n * 480000 + bx * 150;
        const int c = tid >> 2, part = tid & 3;
        const float4* row = (const float4*)(xr + c * 7500);
        for (int j = part; j < 37; j += 4) {  // floats 0..147
            float4 v4 = row[j];
            ushort* dst = &Xl[(j * 4) * 72 + c];
            dst[0]   = f2bf(v4.x);
            dst[72]  = f2bf(v4.y);
            dst[144] = f2bf(v4.z);
            dst[216] = f2bf(v4.w);
        }
        if (tid < 64) {  // tail floats 148,149 of each c-row
            float2 v2 = *(const float2*)(xr + tid * 7500 + 148);
            Xl[148 * 72 + tid] = f2bf(v2.x);
            Xl[149 * 72 + tid] = f2bf(v2.y);
        }
        for (int i = tid; i < 720; i += 256) Xl[10800 + i] = 0;  // rows 150..159
    }
    __syncthreads();

    f32x4 yacc[6][2];
#pragma unroll
    for (int t = 0; t < 6; ++t)
#pragma unroll
        for (int j = 0; j < 2; ++j) yacc[t][j] = (f32x4){0.f, 0.f, 0.f, 0.f};

#pragma unroll
    for (int s = 0; s < 3; ++s) {
#pragma unroll
        for (int t = 0; t < 6; ++t) {
            const int r0 = (t * 25 + col) * 72 + (quad << 3);
            const int r1 = r0 + 16 * 72;
            bf16x8 x00 = *(const bf16x8*)&Xl[r0];
            bf16x8 x01 = *(const bf16x8*)&Xl[r0 + 32];
            bf16x8 x10 = *(const bf16x8*)&Xl[r1];
            bf16x8 x11 = *(const bf16x8*)&Xl[r1 + 32];
            // GEMM1 swapped: D[m=v][n=o] = X^T * W^T = Z^T  (bit-identical MACs)
            f32x4 zA = (f32x4){0.f, 0.f, 0.f, 0.f};
            f32x4 zB = (f32x4){0.f, 0.f, 0.f, 0.f};
            zA = __builtin_amdgcn_mfma_f32_16x16x32_bf16(x00, wf[s * 2 + 0], zA, 0, 0, 0);
            zA = __builtin_amdgcn_mfma_f32_16x16x32_bf16(x01, wf[s * 2 + 1], zA, 0, 0, 0);
            zB = __builtin_amdgcn_mfma_f32_16x16x32_bf16(x10, wf[s * 2 + 0], zB, 0, 0, 0);
            zB = __builtin_amdgcn_mfma_f32_16x16x32_bf16(x11, wf[s * 2 + 1], zB, 0, 0, 0);
            // lane-local pack IS the GEMM2 A-operand (K-permuted table)
            union { unsigned u[4]; bf16x8 v; } zf;
            zf.u[0] = (unsigned)f2bf(zA[0]) | ((unsigned)f2bf(zA[1]) << 16);
            zf.u[1] = (unsigned)f2bf(zA[2]) | ((unsigned)f2bf(zA[3]) << 16);
            zf.u[2] = (unsigned)f2bf(zB[0]) | ((unsigned)f2bf(zB[1]) << 16);
            zf.u[3] = (unsigned)f2bf(zB[2]) | ((unsigned)f2bf(zB[3]) << 16);
            yacc[t][0] = __builtin_amdgcn_mfma_f32_16x16x32_bf16(zf.v, af[s * 2 + 0], yacc[t][0], 0, 0, 0);
            yacc[t][1] = __builtin_amdgcn_mfma_f32_16x16x32_bf16(zf.v, af[s * 2 + 1], yacc[t][1], 0, 0, 0);
        }
    }

    // ---- epilogue ----
    __syncthreads();  // all waves done reading Xl
    ushort* Ys = Xl;  // 64 rows x 150 = 9600 ushorts

    float ssum[4] = {0.f, 0.f, 0.f, 0.f}, ssq[4] = {0.f, 0.f, 0.f, 0.f};
    const int obase = strip + (quad << 2);
#pragma unroll
    for (int t = 0; t < 6; ++t)
#pragma unroll
        for (int nt2 = 0; nt2 < 2; ++nt2) {
            int w = nt2 * 16 + col;
            if (w < 25) {
                f32x4 f = yacc[t][nt2];
#pragma unroll
                for (int r = 0; r < 4; ++r) {
                    float yv = f[r];
                    Ys[(obase + r) * 150 + t * 25 + w] = f2bf(yv);
                    ssum[r] += yv;
                    ssq[r] = fmaf(yv, yv, ssq[r]);
                }
            }
        }
#pragma unroll
    for (int r = 0; r < 4; ++r) {
        float a = ssum[r], b = ssq[r];
        for (int m = 1; m < 16; m <<= 1) {  // reduce over the 16 w-lanes
            a += __shfl_xor(a, m, 64);
            b += __shfl_xor(b, m, 64);
        }
        if (col == 0) {  // unique (wv,quad,r) -> unique o
            sst[obase + r] = a;
            sst[64 + obase + r] = b;
        }
    }
    __syncthreads();
    // natural layout: per o-row, 150 ushorts = 75 uints at 4 B grain.
    // each wave owns its 16 o-rows (strip..strip+15): 1200 uints.
    {
        const unsigned* src = (const unsigned*)Ys;
        for (int idx = lane; idx < 1200; idx += 64) {
            int oo = idx / 75;           // 0..15 (const divide -> magic mul)
            int r2 = idx - oo * 75;
            int o = strip + oo;
            *(unsigned*)(ypre + (size_t)n * 480000 + o * 7500 + bx * 150 + r2 * 2) =
                src[o * 75 + r2];
        }
    }
    const int rep = (bx + blockIdx.y) & 15;
    if (tid < 128) atomicAdd(&stats[rep * 128 + tid], sst[tid]);
}

// ---------------------------------------------------------------------------
// K3: out = relu(sc[o]*bf2f(ypre) + sh[o] + x). Plane-mapped (R5-proven);
// ypre now natural [n][o][t][v] -> plane-contiguous u16x4 reads, no divide.
// BN finalize folded in; out store nontemporal.
// ---------------------------------------------------------------------------
__global__ __launch_bounds__(256) void k_bnrelu_f(const float* __restrict__ x,
                                                  const ushort* __restrict__ ypre,
                                                  const float* __restrict__ stats,
                                                  const float* __restrict__ gamma,
                                                  const float* __restrict__ beta,
                                                  float* __restrict__ out) {
    __shared__ float bsc[2];
    const int plane = blockIdx.x;  // n*64 + o
    const int o = plane & 63;
    const int tid = threadIdx.x;
    if (tid < 16) {
        float su = stats[tid * 128 + o];
        float sq = stats[tid * 128 + 64 + o];
#pragma unroll
        for (int m = 1; m < 16; m <<= 1) {
            su += __shfl_xor(su, m, 64);
            sq += __shfl_xor(sq, m, 64);
        }
        if (tid == 0) {
            const float invn = 1.0f / 480000.0f;  // N*T*V
            float mean = su * invn;
            float var = sq * invn - mean * mean;
            float sc = gamma[o] * rsqrtf(var + 1e-5f);
            bsc[0] = sc;
            bsc[1] = beta[o] - mean * sc;
        }
    }
    __syncthreads();
    const float sc = bsc[0], sh = bsc[1];
    const u16x4* yp = (const u16x4*)(ypre + (size_t)plane * 7500);
    const f32x4* xp = (const f32x4*)(x + (size_t)plane * 7500);
    f32x4* op = (f32x4*)(out + (size_t)plane * 7500);
    for (int j4 = tid; j4 < 1875; j4 += 256) {
        u16x4 yv = yp[j4];
        f32x4 xx = xp[j4];
        f32x4 r;
        r.x = fmaxf(fmaf(bf2f(yv.x), sc, sh) + xx.x, 0.0f);
        r.y = fmaxf(fmaf(bf2f(yv.y), sc, sh) + xx.y, 0.0f);
        r.z = fmaxf(fmaf(bf2f(yv.z), sc, sh) + xx.z, 0.0f);
        r.w = fmaxf(fmaf(bf2f(yv.w), sc, sh) + xx.w, 0.0f);
        __builtin_nontemporal_store(r, &op[j4]);
    }
}

// ---------------------------------------------------------------------------
extern "C" void kernel_launch(void* const* d_in, const int* in_sizes, int n_in,
                              void* d_out, int out_size, void* d_ws, size_t ws_size,
                              hipStream_t stream) {
    const float* x = (const float*)d_in[0];
    const float* PA = (const float*)d_in[1];
    const float* W = (const float*)d_in[2];
    // d_in[3] = b : cancels through training-mode BN -> unused
    const float* gamma = (const float*)d_in[4];
    const float* beta = (const float*)d_in[5];
    float* wsf = (float*)d_ws;
    float* out = (float*)d_out;
    ushort* ypre = (ushort*)((char*)d_ws + 65536);

    k_prep<<<8, 256, 0, stream>>>(PA, W, wsf);
    dim3 g(50, 64);
    k_main16<<<g, 256, 0, stream>>>(x, wsf, ypre, wsf + 2048);
    k_bnrelu_f<<<4096, 256, 0, stream>>>(x, ypre, wsf + 2048, gamma, beta, out);
}